// Round 6
// baseline (453.841 us; speedup 1.0000x reference)
//
#include <hip/hip_runtime.h>
#include <hip/hip_bf16.h>

// GNN decoder: 2x (GCNConv -> BatchNorm[-> ReLU]) on N=100000 nodes, E=1.6M edges.
// Round 6: launch-count 17 -> 11. Stats fused into grid-strided aggregates
// (register accum on part-0 lanes -> LDS block reduce -> XCD-local stat slabs);
// BN scale/shift computed by last block via ticket (removes stats+bnprep kernels
// and their 25.6MB read passes). scan2 folded into scan3. wreorders merged.
// agg2 output bf16. Aggregates are AT the ~3.8 TB/s random-gather fabric
// ceiling (r2/r4/r5 evidence) -- not touched further.
// Carries: XCD-affine CSR build (r4), dinv-prescaled GEMM epilogues (r4),
// bf16 intermediates + no-LDS MFMA GEMMs (r3), CSR gather agg (r2), BN bias
// cancellation (r1).

#define IN_C 128
#define HID_C 128
#define OUT_C2 64
#define BN_EPS 1e-5f
#define NGROUPS 8
#define NSLAB 8
#define AGG_BLOCKS 2048

typedef __attribute__((ext_vector_type(8))) short short8v;
typedef __attribute__((ext_vector_type(4))) float float4v;

__device__ inline ushort f2bf(float f) {
    union { float f; unsigned u; } x; x.f = f;
    return (ushort)((x.u + 0x7fffu + ((x.u >> 16) & 1u)) >> 16);  // RNE
}
__device__ inline float bf2f(ushort u) {
    union { unsigned u; float f; } x; x.u = ((unsigned)u) << 16;
    return x.f;
}

// zero stats slabs + tickets (3458 words) + deg (N int) in one launch
__global__ void init_kernel(float* __restrict__ ws, int* __restrict__ deg, int N) {
    int i = blockIdx.x * blockDim.x + threadIdx.x;
    if (i < 3458) ws[i] = 0.0f;
    if (i < N) deg[i] = 0;
}

// Grouped degree histogram: group g = blockIdx%8 counts dst in [g*gsz,(g+1)*gsz).
// Coalesced int4 streaming reads; atomics land in a ~50KB XCD-local L2 window.
__global__ __launch_bounds__(256) void degree_grouped_kernel(
    const int* __restrict__ dst, int* __restrict__ deg, int E, int gsz)
{
    int g = blockIdx.x & (NGROUPS - 1);
    int bi = blockIdx.x / NGROUPS;
    int bpg = gridDim.x / NGROUPS;
    int lo = g * gsz, hi = lo + gsz;
    int E4 = E & ~3;
    int stride = bpg * 256 * 4;
    for (int i = (bi * 256 + threadIdx.x) * 4; i < E4; i += stride) {
        int4 d = *(const int4*)&dst[i];
        if (d.x >= lo && d.x < hi) atomicAdd(&deg[d.x], 1);
        if (d.y >= lo && d.y < hi) atomicAdd(&deg[d.y], 1);
        if (d.z >= lo && d.z < hi) atomicAdd(&deg[d.z], 1);
        if (d.w >= lo && d.w < hi) atomicAdd(&deg[d.w], 1);
    }
    if (bi == 0 && threadIdx.x < (E & 3)) {
        int d = dst[E4 + threadIdx.x];
        if (d >= lo && d < hi) atomicAdd(&deg[d], 1);
    }
}

// exclusive scan of deg[N] -> row_ptr (per-tile) + tile sums; also emits dinv
__global__ __launch_bounds__(256) void scan1_kernel(const int* __restrict__ in,
                                                    int* __restrict__ out,
                                                    int* __restrict__ tilesums,
                                                    float* __restrict__ dinv, int n)
{
    __shared__ int sdata[256];
    int t = threadIdx.x;
    int idx = blockIdx.x * 1024 + t * 4;
    int4 v = make_int4(0, 0, 0, 0);
    if (idx + 3 < n) v = *(const int4*)&in[idx];
    else {
        if (idx < n)     v.x = in[idx];
        if (idx + 1 < n) v.y = in[idx + 1];
        if (idx + 2 < n) v.z = in[idx + 2];
        if (idx + 3 < n) v.w = in[idx + 3];
    }
    if (idx + 3 < n) {
        *(float4*)&dinv[idx] = make_float4(rsqrtf((float)v.x + 1.0f),
                                           rsqrtf((float)v.y + 1.0f),
                                           rsqrtf((float)v.z + 1.0f),
                                           rsqrtf((float)v.w + 1.0f));
    } else {
        if (idx < n)     dinv[idx]     = rsqrtf((float)v.x + 1.0f);
        if (idx + 1 < n) dinv[idx + 1] = rsqrtf((float)v.y + 1.0f);
        if (idx + 2 < n) dinv[idx + 2] = rsqrtf((float)v.z + 1.0f);
        if (idx + 3 < n) dinv[idx + 3] = rsqrtf((float)v.w + 1.0f);
    }
    int s1 = v.x, s2 = s1 + v.y, s3 = s2 + v.z, s4 = s3 + v.w;
    sdata[t] = s4;
    __syncthreads();
    for (int off = 1; off < 256; off <<= 1) {
        int val = (t >= off) ? sdata[t - off] : 0;
        __syncthreads();
        sdata[t] += val;
        __syncthreads();
    }
    int prev = sdata[t] - s4;
    if (idx < n)     out[idx]     = prev;
    if (idx + 1 < n) out[idx + 1] = prev + s1;
    if (idx + 2 < n) out[idx + 2] = prev + s2;
    if (idx + 3 < n) out[idx + 3] = prev + s3;
    if (t == 255) tilesums[blockIdx.x] = sdata[255];
}

// finalize: every block redundantly scans tilesums (<=256) in LDS, then adds
// tile offsets to row_ptr and seeds cursor. Folds old scan2+scan3.
__global__ __launch_bounds__(256) void scan_fin_kernel(
    int* __restrict__ row_ptr, int* __restrict__ cursor,
    const int* __restrict__ tilesums, int numTiles, int n)
{
    __shared__ int sd[256];
    __shared__ int ex[256];
    int t = threadIdx.x;
    int v = (t < numTiles) ? tilesums[t] : 0;
    sd[t] = v;
    __syncthreads();
    for (int off = 1; off < 256; off <<= 1) {
        int val = (t >= off) ? sd[t - off] : 0;
        __syncthreads();
        sd[t] += val;
        __syncthreads();
    }
    ex[t] = sd[t] - v;      // exclusive
    int total = sd[255];    // grand total (zeros beyond numTiles)
    __syncthreads();
    int i = blockIdx.x * 256 + t;
    if (i == 0) row_ptr[n] = total;
    if (i < n) {
        int rp = row_ptr[i] + ex[i >> 10];
        row_ptr[i] = rp;
        cursor[i] = rp;
    }
}

// Grouped CSR placement, coalesced int4 reads; cursor atomics and csr_src
// writes stay in one XCD's L2 region.
__global__ __launch_bounds__(256) void csr_build_grouped_kernel(
    const int* __restrict__ src, const int* __restrict__ dst,
    int* __restrict__ cursor, int* __restrict__ csr_src, int E, int gsz)
{
    int g = blockIdx.x & (NGROUPS - 1);
    int bi = blockIdx.x / NGROUPS;
    int bpg = gridDim.x / NGROUPS;
    int lo = g * gsz, hi = lo + gsz;
    int E4 = E & ~3;
    int stride = bpg * 256 * 4;
    for (int i = (bi * 256 + threadIdx.x) * 4; i < E4; i += stride) {
        int4 d = *(const int4*)&dst[i];
        int4 s = *(const int4*)&src[i];
        if (d.x >= lo && d.x < hi) csr_src[atomicAdd(&cursor[d.x], 1)] = s.x;
        if (d.y >= lo && d.y < hi) csr_src[atomicAdd(&cursor[d.y], 1)] = s.y;
        if (d.z >= lo && d.z < hi) csr_src[atomicAdd(&cursor[d.z], 1)] = s.z;
        if (d.w >= lo && d.w < hi) csr_src[atomicAdd(&cursor[d.w], 1)] = s.w;
    }
    if (bi == 0 && threadIdx.x < (E & 3)) {
        int i = E4 + threadIdx.x;
        int d = dst[i];
        if (d >= lo && d < hi) csr_src[atomicAdd(&cursor[d], 1)] = src[i];
    }
}

// W[128][OC] f32 -> fragment-ordered bf16: wfrag[kk][ct][lane][e],
// element = W[kk*32 + (lane>>4)*8 + e][ct*16 + (lane&15)]
template <int OC>
__device__ inline void wreorder_impl(const float* __restrict__ W,
                                     ushort* __restrict__ wfrag, int t) {
    constexpr int NCT = OC / 16;
    int lane = t & 63;
    int rest = t >> 6;
    int ct = rest % NCT;
    int kk = rest / NCT;
    int col = ct * 16 + (lane & 15);
    int krow = kk * 32 + (lane >> 4) * 8;
    ushort tmp[8];
    #pragma unroll
    for (int e = 0; e < 8; ++e)
        tmp[e] = f2bf(W[(size_t)(krow + e) * OC + col]);
    uint4 st;
    st.x = (uint)tmp[0] | ((uint)tmp[1] << 16);
    st.y = (uint)tmp[2] | ((uint)tmp[3] << 16);
    st.z = (uint)tmp[4] | ((uint)tmp[5] << 16);
    st.w = (uint)tmp[6] | ((uint)tmp[7] << 16);
    *(uint4*)&wfrag[(size_t)t * 8] = st;
}

// blocks 0-7: W1 (2048 threads), blocks 8-11: W2 (1024 threads)
__global__ void wreorder_both_kernel(const float* __restrict__ W1,
                                     const float* __restrict__ W2,
                                     ushort* __restrict__ wf1,
                                     ushort* __restrict__ wf2) {
    if (blockIdx.x < 8)
        wreorder_impl<HID_C>(W1, wf1, blockIdx.x * 256 + threadIdx.x);
    else
        wreorder_impl<OUT_C2>(W2, wf2, (blockIdx.x - 8) * 256 + threadIdx.x);
}

// Y[N][OC] bf16 = dinv[row] * (A @ W) via mfma_f32_16x16x32_bf16. No LDS.
// BN_IN: A = relu(bf16_in*sc[k]+sh[k]) in f32 -> bf16.
template <int OC, bool BN_IN>
__global__ __launch_bounds__(256) void mfma_gemm_kernel(
    const void* __restrict__ Xv, const ushort* __restrict__ wfrag,
    ushort* __restrict__ Y, const float* __restrict__ dinv,
    const float* __restrict__ sc, const float* __restrict__ sh, int N)
{
    constexpr int NCT = OC / 16;
    int wave = (blockIdx.x * 256 + threadIdx.x) >> 6;
    int lane = threadIdx.x & 63;
    int row16 = wave * 16;
    if (row16 >= N) return;
    int r = lane & 15;
    int g = lane >> 4;
    int row = row16 + r;

    float4v acc[NCT];
    #pragma unroll
    for (int ct = 0; ct < NCT; ++ct) acc[ct] = (float4v){0.f, 0.f, 0.f, 0.f};

    const short8v* wf = (const short8v*)wfrag;

    #pragma unroll
    for (int kk = 0; kk < 4; ++kk) {
        int k0 = kk * 32 + g * 8;
        short8v a;
        if constexpr (!BN_IN) {
            const float* xp = (const float*)Xv + (size_t)row * 128 + k0;
            float4 x0 = *(const float4*)xp;
            float4 x1 = *(const float4*)(xp + 4);
            a[0] = (short)f2bf(x0.x); a[1] = (short)f2bf(x0.y);
            a[2] = (short)f2bf(x0.z); a[3] = (short)f2bf(x0.w);
            a[4] = (short)f2bf(x1.x); a[5] = (short)f2bf(x1.y);
            a[6] = (short)f2bf(x1.z); a[7] = (short)f2bf(x1.w);
        } else {
            const ushort* xp = (const ushort*)Xv + (size_t)row * 128 + k0;
            uint4 v = *(const uint4*)xp;
            float4 s0 = *(const float4*)&sc[k0];
            float4 s1 = *(const float4*)&sc[k0 + 4];
            float4 h0 = *(const float4*)&sh[k0];
            float4 h1 = *(const float4*)&sh[k0 + 4];
            a[0] = (short)f2bf(fmaxf(fmaf(bf2f((ushort)(v.x & 0xffff)), s0.x, h0.x), 0.f));
            a[1] = (short)f2bf(fmaxf(fmaf(bf2f((ushort)(v.x >> 16)),    s0.y, h0.y), 0.f));
            a[2] = (short)f2bf(fmaxf(fmaf(bf2f((ushort)(v.y & 0xffff)), s0.z, h0.z), 0.f));
            a[3] = (short)f2bf(fmaxf(fmaf(bf2f((ushort)(v.y >> 16)),    s0.w, h0.w), 0.f));
            a[4] = (short)f2bf(fmaxf(fmaf(bf2f((ushort)(v.z & 0xffff)), s1.x, h1.x), 0.f));
            a[5] = (short)f2bf(fmaxf(fmaf(bf2f((ushort)(v.z >> 16)),    s1.y, h1.y), 0.f));
            a[6] = (short)f2bf(fmaxf(fmaf(bf2f((ushort)(v.w & 0xffff)), s1.z, h1.z), 0.f));
            a[7] = (short)f2bf(fmaxf(fmaf(bf2f((ushort)(v.w >> 16)),    s1.w, h1.w), 0.f));
        }
        #pragma unroll
        for (int ct = 0; ct < NCT; ++ct) {
            short8v b = wf[((size_t)(kk * NCT + ct)) * 64 + lane];
            acc[ct] = __builtin_amdgcn_mfma_f32_16x16x32_bf16(a, b, acc[ct], 0, 0, 0);
        }
    }
    float di[4];
    #pragma unroll
    for (int i = 0; i < 4; ++i) di[i] = dinv[row16 + g * 4 + i];
    #pragma unroll
    for (int ct = 0; ct < NCT; ++ct) {
        #pragma unroll
        for (int i = 0; i < 4; ++i) {
            int orow = row16 + g * 4 + i;
            Y[(size_t)orow * OC + ct * 16 + r] = f2bf(acc[ct][i] * di[i]);
        }
    }
}

// Aggregate + fused BN stats + last-block BN prep.
// h rows pre-scaled by dinv[src]; out[d] = dinv[d]*(sum_e h[src_e] + h[d]) (bf16).
// Grid-strided (AGG_BLOCKS blocks); part-0 lanes accumulate per-channel
// sum/sumsq in registers, block-reduce in LDS, flush to XCD-local stat slab
// (blockIdx%8). Last block (ticket) computes sc/sh from the slabs.
template <int C>
__global__ __launch_bounds__(256) void aggregate_stats_kernel(
    const ushort* __restrict__ h, const int* __restrict__ row_ptr,
    const int* __restrict__ csr_src, const float* __restrict__ dinv,
    ushort* __restrict__ out, float* __restrict__ stats /* [NSLAB][2C] */,
    const float* __restrict__ gamma, const float* __restrict__ beta,
    float* __restrict__ sc, float* __restrict__ sh,
    int* __restrict__ ticket, int nblocks, int N)
{
    constexpr int TPN = C / 8;     // lanes per row slice: 16 (C=128) / 8 (C=64)
    constexpr int PAR = 64 / TPN;  // edges in flight per unroll step: 4 / 8
    __shared__ float ls[4][2][C];
    __shared__ bool lastblk;
    int wave = threadIdx.x >> 6;
    int lane = threadIdx.x & 63;
    int part = lane / TPN;
    int c0 = (lane % TPN) * 8;
    float sreg[8] = {0.f,0.f,0.f,0.f,0.f,0.f,0.f,0.f};
    float qreg[8] = {0.f,0.f,0.f,0.f,0.f,0.f,0.f,0.f};

    for (int wid = blockIdx.x * 4 + wave; wid < N; wid += gridDim.x * 4) {
        float acc[8] = {0.f,0.f,0.f,0.f,0.f,0.f,0.f,0.f};
        uint4 vself = make_uint4(0u, 0u, 0u, 0u);
        if (part == 0) vself = *(const uint4*)&h[(size_t)wid * C + c0];
        int e = row_ptr[wid] + part;
        int e1 = row_ptr[wid + 1];
        for (; e + PAR < e1; e += 2 * PAR) {
            int s0 = csr_src[e];
            int s1 = csr_src[e + PAR];
            uint4 v0 = *(const uint4*)&h[(size_t)s0 * C + c0];
            uint4 v1 = *(const uint4*)&h[(size_t)s1 * C + c0];
            acc[0] += bf2f((ushort)(v0.x & 0xffff)) + bf2f((ushort)(v1.x & 0xffff));
            acc[1] += bf2f((ushort)(v0.x >> 16))    + bf2f((ushort)(v1.x >> 16));
            acc[2] += bf2f((ushort)(v0.y & 0xffff)) + bf2f((ushort)(v1.y & 0xffff));
            acc[3] += bf2f((ushort)(v0.y >> 16))    + bf2f((ushort)(v1.y >> 16));
            acc[4] += bf2f((ushort)(v0.z & 0xffff)) + bf2f((ushort)(v1.z & 0xffff));
            acc[5] += bf2f((ushort)(v0.z >> 16))    + bf2f((ushort)(v1.z >> 16));
            acc[6] += bf2f((ushort)(v0.w & 0xffff)) + bf2f((ushort)(v1.w & 0xffff));
            acc[7] += bf2f((ushort)(v0.w >> 16))    + bf2f((ushort)(v1.w >> 16));
        }
        if (e < e1) {
            int s = csr_src[e];
            uint4 v = *(const uint4*)&h[(size_t)s * C + c0];
            acc[0] += bf2f((ushort)(v.x & 0xffff));
            acc[1] += bf2f((ushort)(v.x >> 16));
            acc[2] += bf2f((ushort)(v.y & 0xffff));
            acc[3] += bf2f((ushort)(v.y >> 16));
            acc[4] += bf2f((ushort)(v.z & 0xffff));
            acc[5] += bf2f((ushort)(v.z >> 16));
            acc[6] += bf2f((ushort)(v.w & 0xffff));
            acc[7] += bf2f((ushort)(v.w >> 16));
        }
        if (part == 0) {
            acc[0] += bf2f((ushort)(vself.x & 0xffff));
            acc[1] += bf2f((ushort)(vself.x >> 16));
            acc[2] += bf2f((ushort)(vself.y & 0xffff));
            acc[3] += bf2f((ushort)(vself.y >> 16));
            acc[4] += bf2f((ushort)(vself.z & 0xffff));
            acc[5] += bf2f((ushort)(vself.z >> 16));
            acc[6] += bf2f((ushort)(vself.w & 0xffff));
            acc[7] += bf2f((ushort)(vself.w >> 16));
        }
        #pragma unroll
        for (int off = TPN; off < 64; off <<= 1) {
            #pragma unroll
            for (int j = 0; j < 8; ++j)
                acc[j] += __shfl_xor(acc[j], off, 64);
        }
        if (part == 0) {
            float dd = dinv[wid];
            uint4 st;
            #pragma unroll
            for (int j = 0; j < 8; ++j) {
                acc[j] *= dd;
                sreg[j] += acc[j];
                qreg[j] = fmaf(acc[j], acc[j], qreg[j]);
            }
            st.x = (uint)f2bf(acc[0]) | ((uint)f2bf(acc[1]) << 16);
            st.y = (uint)f2bf(acc[2]) | ((uint)f2bf(acc[3]) << 16);
            st.z = (uint)f2bf(acc[4]) | ((uint)f2bf(acc[5]) << 16);
            st.w = (uint)f2bf(acc[6]) | ((uint)f2bf(acc[7]) << 16);
            *(uint4*)&out[(size_t)wid * C + c0] = st;
        }
    }

    // block-level stats reduce -> XCD-local slab
    if (part == 0) {
        #pragma unroll
        for (int j = 0; j < 8; ++j) {
            ls[wave][0][c0 + j] = sreg[j];
            ls[wave][1][c0 + j] = qreg[j];
        }
    }
    __syncthreads();
    float* slab = stats + (size_t)(blockIdx.x & (NSLAB - 1)) * 2 * C;
    if (threadIdx.x < C) {
        int c = threadIdx.x;
        float s = ls[0][0][c] + ls[1][0][c] + ls[2][0][c] + ls[3][0][c];
        float q = ls[0][1][c] + ls[1][1][c] + ls[2][1][c] + ls[3][1][c];
        atomicAdd(&slab[c], s);
        atomicAdd(&slab[C + c], q);
    }
    __syncthreads();  // all block atomics issued & drained before ticket
    if (threadIdx.x == 0) {
        __threadfence();
        int old = atomicAdd(ticket, 1);
        lastblk = (old == nblocks - 1);
    }
    __syncthreads();
    if (lastblk && threadIdx.x < C) {
        int c = threadIdx.x;
        float s = 0.f, q = 0.f;
        #pragma unroll
        for (int k = 0; k < NSLAB; ++k) {
            s += atomicAdd(&stats[(size_t)k * 2 * C + c], 0.0f);       // coherent read
            q += atomicAdd(&stats[(size_t)k * 2 * C + C + c], 0.0f);
        }
        float invN = 1.0f / (float)N;
        float mu = s * invN;
        float var = q * invN - mu * mu;
        float scl = rsqrtf(var + BN_EPS) * gamma[c];
        sc[c] = scl;
        sh[c] = beta[c] - mu * scl;
    }
}

// BN2 apply: bf16 in -> f32 out, 8 channels per thread
__global__ void bn_apply_kernel(const ushort* __restrict__ in, float* __restrict__ out,
                                const float* __restrict__ sc, const float* __restrict__ sh,
                                int N)
{
    int total = N * (OUT_C2 / 8);
    int i = blockIdx.x * blockDim.x + threadIdx.x;
    int stride = gridDim.x * blockDim.x;
    for (; i < total; i += stride) {
        int c0 = (i & 7) * 8;
        uint4 v = *(const uint4*)&in[(size_t)i * 8];
        float4 s0 = *(const float4*)&sc[c0];
        float4 s1 = *(const float4*)&sc[c0 + 4];
        float4 h0 = *(const float4*)&sh[c0];
        float4 h1 = *(const float4*)&sh[c0 + 4];
        float4 o0, o1;
        o0.x = fmaf(bf2f((ushort)(v.x & 0xffff)), s0.x, h0.x);
        o0.y = fmaf(bf2f((ushort)(v.x >> 16)),    s0.y, h0.y);
        o0.z = fmaf(bf2f((ushort)(v.y & 0xffff)), s0.z, h0.z);
        o0.w = fmaf(bf2f((ushort)(v.y >> 16)),    s0.w, h0.w);
        o1.x = fmaf(bf2f((ushort)(v.z & 0xffff)), s1.x, h1.x);
        o1.y = fmaf(bf2f((ushort)(v.z >> 16)),    s1.y, h1.y);
        o1.z = fmaf(bf2f((ushort)(v.w & 0xffff)), s1.z, h1.z);
        o1.w = fmaf(bf2f((ushort)(v.w >> 16)),    s1.w, h1.w);
        *(float4*)&out[(size_t)i * 8] = o0;
        *(float4*)&out[(size_t)i * 8 + 4] = o1;
    }
}

extern "C" void kernel_launch(void* const* d_in, const int* in_sizes, int n_in,
                              void* d_out, int out_size, void* d_ws, size_t ws_size,
                              hipStream_t stream) {
    const float* x      = (const float*)d_in[0];
    const int*   ei     = (const int*)d_in[1];
    const float* W1     = (const float*)d_in[2];
    // d_in[3] = b1: cancels in BN1 -> skipped
    const float* gamma1 = (const float*)d_in[4];
    const float* beta1  = (const float*)d_in[5];
    const float* W2     = (const float*)d_in[6];
    // d_in[7] = b2: cancels in BN2 -> skipped
    const float* gamma2 = (const float*)d_in[8];
    const float* beta2  = (const float*)d_in[9];

    const int N = in_sizes[0] / IN_C;   // 100000 (divisible by 16)
    const int E = in_sizes[1] / 2;      // 1600000
    const int* src = ei;
    const int* dst = ei + E;
    const int gsz = (N + NGROUPS - 1) / NGROUPS;

    // ws layout (4B words):
    float* ws      = (float*)d_ws;
    float* stats1  = ws;                     // [8][256] = 2048
    float* stats2  = ws + 2048;              // [8][128] = 1024
    float* sc1     = ws + 3072;              // 128
    float* sh1     = ws + 3200;              // 128
    float* sc2     = ws + 3328;              // 64
    float* sh2     = ws + 3392;              // 64
    int*   ticket1 = (int*)(ws + 3456);
    int*   ticket2 = (int*)(ws + 3457);
    float* dinv    = ws + 3472;              // N  (16B aligned)
    int*   deg     = (int*)(dinv + N);       // N (aliased as cursor after scan)
    int*   cursor  = deg;
    int*   row_ptr = deg + N;                // N+16
    int*   tilesums = row_ptr + N + 16;      // 256
    int*   csr_src = tilesums + 256;         // E
    ushort* wfrag1 = (ushort*)(csr_src + E);        // 16384 bf16
    ushort* wfrag2 = wfrag1 + 16384;                // 8192 bf16
    ushort* h1     = wfrag2 + 8192;                 // N*128 bf16 (dinv-prescaled)
    ushort* bufB   = h1 + (size_t)N * HID_C;        // N*128 bf16
    ushort* h2     = bufB + (size_t)N * HID_C;      // N*64 bf16 (dinv-prescaled)
    ushort* agg2b  = h2 + (size_t)N * OUT_C2;       // N*64 bf16

    const int numTiles = (N + 1023) / 1024;  // 98 <= 256

    init_kernel<<<(N + 255) / 256, 256, 0, stream>>>(ws, deg, N);
    degree_grouped_kernel<<<2048, 256, 0, stream>>>(dst, deg, E, gsz);
    scan1_kernel<<<numTiles, 256, 0, stream>>>(deg, row_ptr, tilesums, dinv, N);
    scan_fin_kernel<<<(N + 255) / 256, 256, 0, stream>>>(row_ptr, cursor, tilesums, numTiles, N);
    csr_build_grouped_kernel<<<2048, 256, 0, stream>>>(src, dst, cursor, csr_src, E, gsz);
    wreorder_both_kernel<<<12, 256, 0, stream>>>(W1, W2, wfrag1, wfrag2);

    // Layer 1
    mfma_gemm_kernel<HID_C, false><<<(N / 16 + 3) / 4, 256, 0, stream>>>(
        x, wfrag1, h1, dinv, nullptr, nullptr, N);
    aggregate_stats_kernel<HID_C><<<AGG_BLOCKS, 256, 0, stream>>>(
        h1, row_ptr, csr_src, dinv, bufB, stats1, gamma1, beta1, sc1, sh1,
        ticket1, AGG_BLOCKS, N);

    // Layer 2
    mfma_gemm_kernel<OUT_C2, true><<<(N / 16 + 3) / 4, 256, 0, stream>>>(
        bufB, wfrag2, h2, dinv, sc1, sh1, N);
    aggregate_stats_kernel<OUT_C2><<<AGG_BLOCKS, 256, 0, stream>>>(
        h2, row_ptr, csr_src, dinv, agg2b, stats2, gamma2, beta2, sc2, sh2,
        ticket2, AGG_BLOCKS, N);

    bn_apply_kernel<<<2048, 256, 0, stream>>>(agg2b, (float*)d_out, sc2, sh2, N);
}

// Round 7
// 422.238 us; speedup vs baseline: 1.0748x; 1.0748x over previous
//
#include <hip/hip_runtime.h>
#include <hip/hip_bf16.h>

// GNN decoder: 2x (GCNConv -> BatchNorm[-> ReLU]) on N=100000 nodes, E=1.6M edges.
// Round 7: revert r6's grid-strided fused aggregate (it broke latency hiding:
// 3.76->1.53 TB/s). Aggregates back to one-wave-per-node (r5, at the ~3.8 TB/s
// random-gather ceiling). Stats are separate 256-block kernels again, but with
// BN scale/shift prep fused in via last-block ticket (r6-proven). Keep r6 wins:
// merged scan_fin / wreorder / init, bf16 agg2 buffer, bf16-in bn_apply.
// Carries: XCD-affine CSR build + dinv-prescaled GEMMs (r4), bf16 intermediates
// + no-LDS MFMA GEMMs (r3), CSR gather agg (r2), BN bias cancellation (r1).

#define IN_C 128
#define HID_C 128
#define OUT_C2 64
#define BN_EPS 1e-5f
#define NGROUPS 8

typedef __attribute__((ext_vector_type(8))) short short8v;
typedef __attribute__((ext_vector_type(4))) float float4v;

__device__ inline ushort f2bf(float f) {
    union { float f; unsigned u; } x; x.f = f;
    return (ushort)((x.u + 0x7fffu + ((x.u >> 16) & 1u)) >> 16);  // RNE
}
__device__ inline float bf2f(ushort u) {
    union { unsigned u; float f; } x; x.u = ((unsigned)u) << 16;
    return x.f;
}

// zero stats1/stats2/tickets (ws[0:770)) + deg (N int) in one launch
__global__ void init_kernel(float* __restrict__ ws, int* __restrict__ deg, int N) {
    int i = blockIdx.x * blockDim.x + threadIdx.x;
    if (i < 770) ws[i] = 0.0f;
    if (i < N) deg[i] = 0;
}

// Grouped degree histogram: group g = blockIdx%8 counts dst in [g*gsz,(g+1)*gsz).
__global__ __launch_bounds__(256) void degree_grouped_kernel(
    const int* __restrict__ dst, int* __restrict__ deg, int E, int gsz)
{
    int g = blockIdx.x & (NGROUPS - 1);
    int bi = blockIdx.x / NGROUPS;
    int bpg = gridDim.x / NGROUPS;
    int lo = g * gsz, hi = lo + gsz;
    int E4 = E & ~3;
    int stride = bpg * 256 * 4;
    for (int i = (bi * 256 + threadIdx.x) * 4; i < E4; i += stride) {
        int4 d = *(const int4*)&dst[i];
        if (d.x >= lo && d.x < hi) atomicAdd(&deg[d.x], 1);
        if (d.y >= lo && d.y < hi) atomicAdd(&deg[d.y], 1);
        if (d.z >= lo && d.z < hi) atomicAdd(&deg[d.z], 1);
        if (d.w >= lo && d.w < hi) atomicAdd(&deg[d.w], 1);
    }
    if (bi == 0 && threadIdx.x < (E & 3)) {
        int d = dst[E4 + threadIdx.x];
        if (d >= lo && d < hi) atomicAdd(&deg[d], 1);
    }
}

// exclusive scan of deg[N] -> row_ptr (per-tile) + tile sums; also emits dinv
__global__ __launch_bounds__(256) void scan1_kernel(const int* __restrict__ in,
                                                    int* __restrict__ out,
                                                    int* __restrict__ tilesums,
                                                    float* __restrict__ dinv, int n)
{
    __shared__ int sdata[256];
    int t = threadIdx.x;
    int idx = blockIdx.x * 1024 + t * 4;
    int4 v = make_int4(0, 0, 0, 0);
    if (idx + 3 < n) v = *(const int4*)&in[idx];
    else {
        if (idx < n)     v.x = in[idx];
        if (idx + 1 < n) v.y = in[idx + 1];
        if (idx + 2 < n) v.z = in[idx + 2];
        if (idx + 3 < n) v.w = in[idx + 3];
    }
    if (idx + 3 < n) {
        *(float4*)&dinv[idx] = make_float4(rsqrtf((float)v.x + 1.0f),
                                           rsqrtf((float)v.y + 1.0f),
                                           rsqrtf((float)v.z + 1.0f),
                                           rsqrtf((float)v.w + 1.0f));
    } else {
        if (idx < n)     dinv[idx]     = rsqrtf((float)v.x + 1.0f);
        if (idx + 1 < n) dinv[idx + 1] = rsqrtf((float)v.y + 1.0f);
        if (idx + 2 < n) dinv[idx + 2] = rsqrtf((float)v.z + 1.0f);
        if (idx + 3 < n) dinv[idx + 3] = rsqrtf((float)v.w + 1.0f);
    }
    int s1 = v.x, s2 = s1 + v.y, s3 = s2 + v.z, s4 = s3 + v.w;
    sdata[t] = s4;
    __syncthreads();
    for (int off = 1; off < 256; off <<= 1) {
        int val = (t >= off) ? sdata[t - off] : 0;
        __syncthreads();
        sdata[t] += val;
        __syncthreads();
    }
    int prev = sdata[t] - s4;
    if (idx < n)     out[idx]     = prev;
    if (idx + 1 < n) out[idx + 1] = prev + s1;
    if (idx + 2 < n) out[idx + 2] = prev + s2;
    if (idx + 3 < n) out[idx + 3] = prev + s3;
    if (t == 255) tilesums[blockIdx.x] = sdata[255];
}

// finalize: every block redundantly scans tilesums (<=256) in LDS, then adds
// tile offsets to row_ptr and seeds cursor. (folds old scan2+scan3)
__global__ __launch_bounds__(256) void scan_fin_kernel(
    int* __restrict__ row_ptr, int* __restrict__ cursor,
    const int* __restrict__ tilesums, int numTiles, int n)
{
    __shared__ int sd[256];
    __shared__ int ex[256];
    int t = threadIdx.x;
    int v = (t < numTiles) ? tilesums[t] : 0;
    sd[t] = v;
    __syncthreads();
    for (int off = 1; off < 256; off <<= 1) {
        int val = (t >= off) ? sd[t - off] : 0;
        __syncthreads();
        sd[t] += val;
        __syncthreads();
    }
    ex[t] = sd[t] - v;
    int total = sd[255];
    __syncthreads();
    int i = blockIdx.x * 256 + t;
    if (i == 0) row_ptr[n] = total;
    if (i < n) {
        int rp = row_ptr[i] + ex[i >> 10];
        row_ptr[i] = rp;
        cursor[i] = rp;
    }
}

// Grouped CSR placement; cursor atomics and csr_src writes stay XCD-local.
__global__ __launch_bounds__(256) void csr_build_grouped_kernel(
    const int* __restrict__ src, const int* __restrict__ dst,
    int* __restrict__ cursor, int* __restrict__ csr_src, int E, int gsz)
{
    int g = blockIdx.x & (NGROUPS - 1);
    int bi = blockIdx.x / NGROUPS;
    int bpg = gridDim.x / NGROUPS;
    int lo = g * gsz, hi = lo + gsz;
    int E4 = E & ~3;
    int stride = bpg * 256 * 4;
    for (int i = (bi * 256 + threadIdx.x) * 4; i < E4; i += stride) {
        int4 d = *(const int4*)&dst[i];
        int4 s = *(const int4*)&src[i];
        if (d.x >= lo && d.x < hi) csr_src[atomicAdd(&cursor[d.x], 1)] = s.x;
        if (d.y >= lo && d.y < hi) csr_src[atomicAdd(&cursor[d.y], 1)] = s.y;
        if (d.z >= lo && d.z < hi) csr_src[atomicAdd(&cursor[d.z], 1)] = s.z;
        if (d.w >= lo && d.w < hi) csr_src[atomicAdd(&cursor[d.w], 1)] = s.w;
    }
    if (bi == 0 && threadIdx.x < (E & 3)) {
        int i = E4 + threadIdx.x;
        int d = dst[i];
        if (d >= lo && d < hi) csr_src[atomicAdd(&cursor[d], 1)] = src[i];
    }
}

// W[128][OC] f32 -> fragment-ordered bf16
template <int OC>
__device__ inline void wreorder_impl(const float* __restrict__ W,
                                     ushort* __restrict__ wfrag, int t) {
    constexpr int NCT = OC / 16;
    int lane = t & 63;
    int rest = t >> 6;
    int ct = rest % NCT;
    int kk = rest / NCT;
    int col = ct * 16 + (lane & 15);
    int krow = kk * 32 + (lane >> 4) * 8;
    ushort tmp[8];
    #pragma unroll
    for (int e = 0; e < 8; ++e)
        tmp[e] = f2bf(W[(size_t)(krow + e) * OC + col]);
    uint4 st;
    st.x = (uint)tmp[0] | ((uint)tmp[1] << 16);
    st.y = (uint)tmp[2] | ((uint)tmp[3] << 16);
    st.z = (uint)tmp[4] | ((uint)tmp[5] << 16);
    st.w = (uint)tmp[6] | ((uint)tmp[7] << 16);
    *(uint4*)&wfrag[(size_t)t * 8] = st;
}

__global__ void wreorder_both_kernel(const float* __restrict__ W1,
                                     const float* __restrict__ W2,
                                     ushort* __restrict__ wf1,
                                     ushort* __restrict__ wf2) {
    if (blockIdx.x < 8)
        wreorder_impl<HID_C>(W1, wf1, blockIdx.x * 256 + threadIdx.x);
    else
        wreorder_impl<OUT_C2>(W2, wf2, (blockIdx.x - 8) * 256 + threadIdx.x);
}

// Y[N][OC] bf16 = dinv[row] * (A @ W) via mfma_f32_16x16x32_bf16. No LDS.
template <int OC, bool BN_IN>
__global__ __launch_bounds__(256) void mfma_gemm_kernel(
    const void* __restrict__ Xv, const ushort* __restrict__ wfrag,
    ushort* __restrict__ Y, const float* __restrict__ dinv,
    const float* __restrict__ sc, const float* __restrict__ sh, int N)
{
    constexpr int NCT = OC / 16;
    int wave = (blockIdx.x * 256 + threadIdx.x) >> 6;
    int lane = threadIdx.x & 63;
    int row16 = wave * 16;
    if (row16 >= N) return;
    int r = lane & 15;
    int g = lane >> 4;
    int row = row16 + r;

    float4v acc[NCT];
    #pragma unroll
    for (int ct = 0; ct < NCT; ++ct) acc[ct] = (float4v){0.f, 0.f, 0.f, 0.f};

    const short8v* wf = (const short8v*)wfrag;

    #pragma unroll
    for (int kk = 0; kk < 4; ++kk) {
        int k0 = kk * 32 + g * 8;
        short8v a;
        if constexpr (!BN_IN) {
            const float* xp = (const float*)Xv + (size_t)row * 128 + k0;
            float4 x0 = *(const float4*)xp;
            float4 x1 = *(const float4*)(xp + 4);
            a[0] = (short)f2bf(x0.x); a[1] = (short)f2bf(x0.y);
            a[2] = (short)f2bf(x0.z); a[3] = (short)f2bf(x0.w);
            a[4] = (short)f2bf(x1.x); a[5] = (short)f2bf(x1.y);
            a[6] = (short)f2bf(x1.z); a[7] = (short)f2bf(x1.w);
        } else {
            const ushort* xp = (const ushort*)Xv + (size_t)row * 128 + k0;
            uint4 v = *(const uint4*)xp;
            float4 s0 = *(const float4*)&sc[k0];
            float4 s1 = *(const float4*)&sc[k0 + 4];
            float4 h0 = *(const float4*)&sh[k0];
            float4 h1 = *(const float4*)&sh[k0 + 4];
            a[0] = (short)f2bf(fmaxf(fmaf(bf2f((ushort)(v.x & 0xffff)), s0.x, h0.x), 0.f));
            a[1] = (short)f2bf(fmaxf(fmaf(bf2f((ushort)(v.x >> 16)),    s0.y, h0.y), 0.f));
            a[2] = (short)f2bf(fmaxf(fmaf(bf2f((ushort)(v.y & 0xffff)), s0.z, h0.z), 0.f));
            a[3] = (short)f2bf(fmaxf(fmaf(bf2f((ushort)(v.y >> 16)),    s0.w, h0.w), 0.f));
            a[4] = (short)f2bf(fmaxf(fmaf(bf2f((ushort)(v.z & 0xffff)), s1.x, h1.x), 0.f));
            a[5] = (short)f2bf(fmaxf(fmaf(bf2f((ushort)(v.z >> 16)),    s1.y, h1.y), 0.f));
            a[6] = (short)f2bf(fmaxf(fmaf(bf2f((ushort)(v.w & 0xffff)), s1.z, h1.z), 0.f));
            a[7] = (short)f2bf(fmaxf(fmaf(bf2f((ushort)(v.w >> 16)),    s1.w, h1.w), 0.f));
        }
        #pragma unroll
        for (int ct = 0; ct < NCT; ++ct) {
            short8v b = wf[((size_t)(kk * NCT + ct)) * 64 + lane];
            acc[ct] = __builtin_amdgcn_mfma_f32_16x16x32_bf16(a, b, acc[ct], 0, 0, 0);
        }
    }
    float di[4];
    #pragma unroll
    for (int i = 0; i < 4; ++i) di[i] = dinv[row16 + g * 4 + i];
    #pragma unroll
    for (int ct = 0; ct < NCT; ++ct) {
        #pragma unroll
        for (int i = 0; i < 4; ++i) {
            int orow = row16 + g * 4 + i;
            Y[(size_t)orow * OC + ct * 16 + r] = f2bf(acc[ct][i] * di[i]);
        }
    }
}

// r5 aggregate: one wave per node, 2x-unrolled gather, bf16 out.
// h rows pre-scaled by dinv[src]; out[d] = dinv[d]*(sum_e h[src_e] + h[d]).
template <int C>
__global__ __launch_bounds__(256) void aggregate_kernel(
    const ushort* __restrict__ h, const int* __restrict__ row_ptr,
    const int* __restrict__ csr_src, const float* __restrict__ dinv,
    ushort* __restrict__ out, int N)
{
    constexpr int TPN = C / 8;
    constexpr int PAR = 64 / TPN;
    int wid = (blockIdx.x * 256 + threadIdx.x) >> 6;
    if (wid >= N) return;
    int lane = threadIdx.x & 63;
    int part = lane / TPN;
    int c0 = (lane % TPN) * 8;
    float acc[8] = {0.f, 0.f, 0.f, 0.f, 0.f, 0.f, 0.f, 0.f};

    uint4 vself = make_uint4(0u, 0u, 0u, 0u);
    if (part == 0) vself = *(const uint4*)&h[(size_t)wid * C + c0];

    int e = row_ptr[wid] + part;
    int e1 = row_ptr[wid + 1];
    for (; e + PAR < e1; e += 2 * PAR) {
        int s0 = csr_src[e];
        int s1 = csr_src[e + PAR];
        uint4 v0 = *(const uint4*)&h[(size_t)s0 * C + c0];
        uint4 v1 = *(const uint4*)&h[(size_t)s1 * C + c0];
        acc[0] += bf2f((ushort)(v0.x & 0xffff)) + bf2f((ushort)(v1.x & 0xffff));
        acc[1] += bf2f((ushort)(v0.x >> 16))    + bf2f((ushort)(v1.x >> 16));
        acc[2] += bf2f((ushort)(v0.y & 0xffff)) + bf2f((ushort)(v1.y & 0xffff));
        acc[3] += bf2f((ushort)(v0.y >> 16))    + bf2f((ushort)(v1.y >> 16));
        acc[4] += bf2f((ushort)(v0.z & 0xffff)) + bf2f((ushort)(v1.z & 0xffff));
        acc[5] += bf2f((ushort)(v0.z >> 16))    + bf2f((ushort)(v1.z >> 16));
        acc[6] += bf2f((ushort)(v0.w & 0xffff)) + bf2f((ushort)(v1.w & 0xffff));
        acc[7] += bf2f((ushort)(v0.w >> 16))    + bf2f((ushort)(v1.w >> 16));
    }
    if (e < e1) {
        int s = csr_src[e];
        uint4 v = *(const uint4*)&h[(size_t)s * C + c0];
        acc[0] += bf2f((ushort)(v.x & 0xffff));
        acc[1] += bf2f((ushort)(v.x >> 16));
        acc[2] += bf2f((ushort)(v.y & 0xffff));
        acc[3] += bf2f((ushort)(v.y >> 16));
        acc[4] += bf2f((ushort)(v.z & 0xffff));
        acc[5] += bf2f((ushort)(v.z >> 16));
        acc[6] += bf2f((ushort)(v.w & 0xffff));
        acc[7] += bf2f((ushort)(v.w >> 16));
    }
    if (part == 0) {
        acc[0] += bf2f((ushort)(vself.x & 0xffff));
        acc[1] += bf2f((ushort)(vself.x >> 16));
        acc[2] += bf2f((ushort)(vself.y & 0xffff));
        acc[3] += bf2f((ushort)(vself.y >> 16));
        acc[4] += bf2f((ushort)(vself.z & 0xffff));
        acc[5] += bf2f((ushort)(vself.z >> 16));
        acc[6] += bf2f((ushort)(vself.w & 0xffff));
        acc[7] += bf2f((ushort)(vself.w >> 16));
    }
    #pragma unroll
    for (int off = TPN; off < 64; off <<= 1) {
        #pragma unroll
        for (int j = 0; j < 8; ++j)
            acc[j] += __shfl_xor(acc[j], off, 64);
    }
    if (part == 0) {
        float dd = dinv[wid];
        uint4 st;
        #pragma unroll
        for (int j = 0; j < 8; ++j) acc[j] *= dd;
        st.x = (uint)f2bf(acc[0]) | ((uint)f2bf(acc[1]) << 16);
        st.y = (uint)f2bf(acc[2]) | ((uint)f2bf(acc[3]) << 16);
        st.z = (uint)f2bf(acc[4]) | ((uint)f2bf(acc[5]) << 16);
        st.w = (uint)f2bf(acc[6]) | ((uint)f2bf(acc[7]) << 16);
        *(uint4*)&out[(size_t)wid * C + c0] = st;
    }
}

// Per-channel sum & sumsq over bf16 rows + last-block BN scale/shift prep.
template <int C>
__global__ __launch_bounds__(256) void stats_prep_kernel(
    const ushort* __restrict__ h, float* __restrict__ sums /* [2C] */,
    const float* __restrict__ gamma, const float* __restrict__ beta,
    float* __restrict__ sc, float* __restrict__ sh,
    int* __restrict__ ticket, int nblocks, int N)
{
    constexpr int CG = C / 8;
    constexpr int RPB = 256 / CG;
    __shared__ float red[RPB][CG][16];
    __shared__ bool lastblk;
    int tid = threadIdx.x;
    int cg = tid % CG, rg = tid / CG;
    int c0 = cg * 8;
    float s[8] = {0.f,0.f,0.f,0.f,0.f,0.f,0.f,0.f};
    float q[8] = {0.f,0.f,0.f,0.f,0.f,0.f,0.f,0.f};
    for (int r = blockIdx.x * RPB + rg; r < N; r += gridDim.x * RPB) {
        uint4 v = *(const uint4*)&h[(size_t)r * C + c0];
        float f0 = bf2f((ushort)(v.x & 0xffff)), f1 = bf2f((ushort)(v.x >> 16));
        float f2 = bf2f((ushort)(v.y & 0xffff)), f3 = bf2f((ushort)(v.y >> 16));
        float f4 = bf2f((ushort)(v.z & 0xffff)), f5 = bf2f((ushort)(v.z >> 16));
        float f6 = bf2f((ushort)(v.w & 0xffff)), f7 = bf2f((ushort)(v.w >> 16));
        s[0]+=f0; s[1]+=f1; s[2]+=f2; s[3]+=f3; s[4]+=f4; s[5]+=f5; s[6]+=f6; s[7]+=f7;
        q[0]=fmaf(f0,f0,q[0]); q[1]=fmaf(f1,f1,q[1]); q[2]=fmaf(f2,f2,q[2]); q[3]=fmaf(f3,f3,q[3]);
        q[4]=fmaf(f4,f4,q[4]); q[5]=fmaf(f5,f5,q[5]); q[6]=fmaf(f6,f6,q[6]); q[7]=fmaf(f7,f7,q[7]);
    }
    #pragma unroll
    for (int j = 0; j < 8; ++j) { red[rg][cg][j] = s[j]; red[rg][cg][8 + j] = q[j]; }
    __syncthreads();
    if (rg == 0) {
        float a[16];
        #pragma unroll
        for (int i = 0; i < 16; ++i) a[i] = red[0][cg][i];
        for (int r2 = 1; r2 < RPB; ++r2)
            #pragma unroll
            for (int i = 0; i < 16; ++i) a[i] += red[r2][cg][i];
        #pragma unroll
        for (int j = 0; j < 8; ++j) {
            atomicAdd(&sums[c0 + j], a[j]);
            atomicAdd(&sums[C + c0 + j], a[8 + j]);
        }
    }
    __syncthreads();
    if (tid == 0) {
        __threadfence();
        int old = atomicAdd(ticket, 1);
        lastblk = (old == nblocks - 1);
    }
    __syncthreads();
    if (lastblk && tid < C) {
        float sv = atomicAdd(&sums[tid], 0.0f);        // coherent reads
        float qv = atomicAdd(&sums[C + tid], 0.0f);
        float invN = 1.0f / (float)N;
        float mu = sv * invN;
        float var = qv * invN - mu * mu;
        float scl = rsqrtf(var + BN_EPS) * gamma[tid];
        sc[tid] = scl;
        sh[tid] = beta[tid] - mu * scl;
    }
}

// BN2 apply: bf16 in -> f32 out, 8 channels per thread
__global__ void bn_apply_kernel(const ushort* __restrict__ in, float* __restrict__ out,
                                const float* __restrict__ sc, const float* __restrict__ sh,
                                int N)
{
    int total = N * (OUT_C2 / 8);
    int i = blockIdx.x * blockDim.x + threadIdx.x;
    int stride = gridDim.x * blockDim.x;
    for (; i < total; i += stride) {
        int c0 = (i & 7) * 8;
        uint4 v = *(const uint4*)&in[(size_t)i * 8];
        float4 s0 = *(const float4*)&sc[c0];
        float4 s1 = *(const float4*)&sc[c0 + 4];
        float4 h0 = *(const float4*)&sh[c0];
        float4 h1 = *(const float4*)&sh[c0 + 4];
        float4 o0, o1;
        o0.x = fmaf(bf2f((ushort)(v.x & 0xffff)), s0.x, h0.x);
        o0.y = fmaf(bf2f((ushort)(v.x >> 16)),    s0.y, h0.y);
        o0.z = fmaf(bf2f((ushort)(v.y & 0xffff)), s0.z, h0.z);
        o0.w = fmaf(bf2f((ushort)(v.y >> 16)),    s0.w, h0.w);
        o1.x = fmaf(bf2f((ushort)(v.z & 0xffff)), s1.x, h1.x);
        o1.y = fmaf(bf2f((ushort)(v.z >> 16)),    s1.y, h1.y);
        o1.z = fmaf(bf2f((ushort)(v.w & 0xffff)), s1.z, h1.z);
        o1.w = fmaf(bf2f((ushort)(v.w >> 16)),    s1.w, h1.w);
        *(float4*)&out[(size_t)i * 8] = o0;
        *(float4*)&out[(size_t)i * 8 + 4] = o1;
    }
}

extern "C" void kernel_launch(void* const* d_in, const int* in_sizes, int n_in,
                              void* d_out, int out_size, void* d_ws, size_t ws_size,
                              hipStream_t stream) {
    const float* x      = (const float*)d_in[0];
    const int*   ei     = (const int*)d_in[1];
    const float* W1     = (const float*)d_in[2];
    // d_in[3] = b1: cancels in BN1 -> skipped
    const float* gamma1 = (const float*)d_in[4];
    const float* beta1  = (const float*)d_in[5];
    const float* W2     = (const float*)d_in[6];
    // d_in[7] = b2: cancels in BN2 -> skipped
    const float* gamma2 = (const float*)d_in[8];
    const float* beta2  = (const float*)d_in[9];

    const int N = in_sizes[0] / IN_C;   // 100000 (divisible by 16)
    const int E = in_sizes[1] / 2;      // 1600000
    const int* src = ei;
    const int* dst = ei + E;
    const int gsz = (N + NGROUPS - 1) / NGROUPS;

    // ws layout (4B words):
    float* ws      = (float*)d_ws;
    float* stats1  = ws;                     // 256
    float* stats2  = ws + 256;               // 128
    float* sc1     = ws + 384;               // 128
    float* sh1     = ws + 512;               // 128
    float* sc2     = ws + 640;               // 64
    float* sh2     = ws + 704;               // 64
    int*   ticket1 = (int*)(ws + 768);
    int*   ticket2 = (int*)(ws + 769);
    float* dinv    = ws + 784;               // N (16B aligned)
    int*   deg     = (int*)(dinv + N);       // N (aliased as cursor after scan)
    int*   cursor  = deg;
    int*   row_ptr = deg + N;                // N+16
    int*   tilesums = row_ptr + N + 16;      // 256
    int*   csr_src = tilesums + 256;         // E
    ushort* wfrag1 = (ushort*)(csr_src + E);        // 16384 bf16
    ushort* wfrag2 = wfrag1 + 16384;                // 8192 bf16
    ushort* h1     = wfrag2 + 8192;                 // N*128 bf16 (dinv-prescaled)
    ushort* bufB   = h1 + (size_t)N * HID_C;        // N*128 bf16
    ushort* h2     = bufB + (size_t)N * HID_C;      // N*64 bf16 (dinv-prescaled)
    ushort* agg2b  = h2 + (size_t)N * OUT_C2;       // N*64 bf16

    const int numTiles = (N + 1023) / 1024;  // 98 <= 256

    init_kernel<<<(N + 255) / 256, 256, 0, stream>>>(ws, deg, N);
    degree_grouped_kernel<<<2048, 256, 0, stream>>>(dst, deg, E, gsz);
    scan1_kernel<<<numTiles, 256, 0, stream>>>(deg, row_ptr, tilesums, dinv, N);
    scan_fin_kernel<<<(N + 255) / 256, 256, 0, stream>>>(row_ptr, cursor, tilesums, numTiles, N);
    csr_build_grouped_kernel<<<2048, 256, 0, stream>>>(src, dst, cursor, csr_src, E, gsz);
    wreorder_both_kernel<<<12, 256, 0, stream>>>(W1, W2, wfrag1, wfrag2);

    // Layer 1
    mfma_gemm_kernel<HID_C, false><<<(N / 16 + 3) / 4, 256, 0, stream>>>(
        x, wfrag1, h1, dinv, nullptr, nullptr, N);
    aggregate_kernel<HID_C><<<(N + 3) / 4, 256, 0, stream>>>(
        h1, row_ptr, csr_src, dinv, bufB, N);
    stats_prep_kernel<HID_C><<<256, 256, 0, stream>>>(
        bufB, stats1, gamma1, beta1, sc1, sh1, ticket1, 256, N);

    // Layer 2
    mfma_gemm_kernel<OUT_C2, true><<<(N / 16 + 3) / 4, 256, 0, stream>>>(
        bufB, wfrag2, h2, dinv, sc1, sh1, N);
    aggregate_kernel<OUT_C2><<<(N + 3) / 4, 256, 0, stream>>>(
        h2, row_ptr, csr_src, dinv, agg2b, N);
    stats_prep_kernel<OUT_C2><<<256, 256, 0, stream>>>(
        agg2b, stats2, gamma2, beta2, sc2, sh2, ticket2, 256, N);

    bn_apply_kernel<<<2048, 256, 0, stream>>>(agg2b, (float*)d_out, sc2, sh2, N);
}